// Round 4
// baseline (502.526 us; speedup 1.0000x reference)
//
#include <hip/hip_runtime.h>
#include <hip/hip_bf16.h>

static constexpr int KD  = 64;    // feature dim
static constexpr int KIN = 256;   // concat dim
static constexpr int KH  = 64;    // hidden dim

typedef __attribute__((ext_vector_type(8))) short bf16x8;
typedef __attribute__((ext_vector_type(4))) float f32x4;

__device__ inline unsigned short f2bf(float f) {
  union { float f; unsigned u; } uf; uf.f = f;
  unsigned u = uf.u;
  return (unsigned short)((u + 0x7FFFu + ((u >> 16) & 1u)) >> 16);
}
__device__ inline float bf2f(unsigned short h) {
  union { unsigned u; float f; } x; x.u = ((unsigned)h) << 16; return x.f;
}
__device__ inline bf16x8 pack8(const float* p) {
  float4 lo = *(const float4*)p;
  float4 hi = *(const float4*)(p + 4);
  bf16x8 v;
  v[0] = (short)f2bf(lo.x); v[1] = (short)f2bf(lo.y);
  v[2] = (short)f2bf(lo.z); v[3] = (short)f2bf(lo.w);
  v[4] = (short)f2bf(hi.x); v[5] = (short)f2bf(hi.y);
  v[6] = (short)f2bf(hi.z); v[7] = (short)f2bf(hi.w);
  return v;
}
__device__ inline float sigm(float x) { return 1.0f / (1.0f + __expf(-x)); }
__device__ inline float silu_(float x) { return x * sigm(x); }

// K0: wc1t/wg1t natural [h][k]; wc2t/wg2t PERMUTED [d][k'] with
// sigma(k') = 32*(k'>>5) + 16*((k'>>2)&1) + 4*((k'>>3)&3) + (k'&3);
// wot natural [d][h] (used by k_aggout).
__global__ void k_prep(const float* __restrict__ wc1, const float* __restrict__ wg1,
                       const float* __restrict__ wc2, const float* __restrict__ wg2,
                       const float* __restrict__ wo,
                       unsigned short* __restrict__ wc1t, unsigned short* __restrict__ wg1t,
                       unsigned short* __restrict__ wc2t, unsigned short* __restrict__ wg2t,
                       unsigned short* __restrict__ wot) {
  int t = blockIdx.x * blockDim.x + threadIdx.x;
  if (t < KIN * KH) {
    int h = t >> 8, k = t & 255;
    wc1t[t] = f2bf(wc1[k * KH + h]);
    wg1t[t] = f2bf(wg1[k * KH + h]);
  }
  if (t < KH * KD) {
    int d = t >> 6, kp = t & 63;
    int h = 32 * (kp >> 5) + 16 * ((kp >> 2) & 1) + 4 * ((kp >> 3) & 3) + (kp & 3);
    wc2t[t] = f2bf(wc2[h * KD + d]);
    wg2t[t] = f2bf(wg2[h * KD + d]);
    int n = t >> 6, k = t & 63;
    wot[t]  = f2bf(wo[k * KD + n]);
  }
}

// K1: transposed pipeline (angles = MFMA columns). W1 in LDS; W2 permuted in regs.
__global__ __launch_bounds__(256, 2) void k_angle(
    const float* __restrict__ atom, const float* __restrict__ bond,
    const float* __restrict__ bwt,  const float* __restrict__ ang,
    const int* __restrict__ bgr,
    const unsigned short* __restrict__ wc1t, const unsigned short* __restrict__ wg1t,
    const unsigned short* __restrict__ wc2t, const unsigned short* __restrict__ wg2t,
    const float* __restrict__ bc1, const float* __restrict__ bc2,
    const float* __restrict__ bg1, const float* __restrict__ bg2,
    unsigned short* __restrict__ upd, int ng) {
  constexpr int SP = 264;                      // LDS row stride (shorts): 528B = 33*16
  __shared__ unsigned short w1lds[128 * SP];   // rows 0-63 core, 64-127 gate

  const int tid  = threadIdx.x;
  const int wave = tid >> 6;
  const int lane = tid & 63;
  const int q = lane & 15;      // angle column within wave's 16
  const int p = lane >> 4;      // k-chunk selector

  // stage W1cat (64KB) once per block, cooperatively
  for (int c = tid; c < 4096; c += 256) {
    const int row = c >> 5, col = (c & 31) * 8;
    const unsigned short* src = (row < 64) ? (wc1t + row * KIN + col)
                                           : (wg1t + (row - 64) * KIN + col);
    *(bf16x8*)&w1lds[row * SP + col] = *(const bf16x8*)src;
  }
  __syncthreads();

  // loop-invariant W2 A-fragments (permuted layout): lane reads [q+16n2][32s2+8p..+8]
  bf16x8 w2c[4][2], w2g[4][2];
#pragma unroll
  for (int n2 = 0; n2 < 4; n2++)
#pragma unroll
    for (int s2 = 0; s2 < 2; s2++) {
      const int o = (q + 16 * n2) * KH + 32 * s2 + 8 * p;
      w2c[n2][s2] = *(const bf16x8*)(wc2t + o);
      w2g[n2][s2] = *(const bf16x8*)(wg2t + o);
    }

  const int ntile = (ng + 63) >> 6;
  for (int tile = blockIdx.x; tile < ntile; tile += gridDim.x) {
    const int g0 = tile * 64 + wave * 16 + q;
    const int g  = (g0 < ng) ? g0 : (ng - 1);
    const int ci = bgr[3 * g + 0];
    const int bi = bgr[3 * g + 1];
    const int bj = bgr[3 * g + 2];

    // gather B1 fragments: T[g][k], k = 32s + 8p + e
    bf16x8 a1[8];
    {
      const float* p0 = bond + (long)bi * KD;
      const float* p1 = bond + (long)bj * KD;
      const float* p2 = ang  + (long)g  * KD;
      const float* p3 = atom + (long)ci * KD;
      const int off8 = p * 8;
      a1[0] = pack8(p0 + off8);      a1[1] = pack8(p0 + 32 + off8);
      a1[2] = pack8(p1 + off8);      a1[3] = pack8(p1 + 32 + off8);
      a1[4] = pack8(p2 + off8);      a1[5] = pack8(p2 + 32 + off8);
      a1[6] = pack8(p3 + off8);      a1[7] = pack8(p3 + 32 + off8);
    }

    // GEMM1: H[h][g] — acc1*[n][j] = H[16n+4p+j][g(q)]
    f32x4 hc[4], hg[4];
#pragma unroll
    for (int n = 0; n < 4; n++) {
      hc[n] = (f32x4&)*(const float4*)(bc1 + 16 * n + 4 * p);
      hg[n] = (f32x4&)*(const float4*)(bg1 + 16 * n + 4 * p);
    }
#pragma unroll
    for (int s = 0; s < 8; s++) {
      const int kc = 32 * s + 8 * p;
#pragma unroll
      for (int n = 0; n < 4; n++) {
        bf16x8 af = *(const bf16x8*)&w1lds[(16 * n + q) * SP + kc];
        hc[n] = __builtin_amdgcn_mfma_f32_16x16x32_bf16(af, a1[s], hc[n], 0, 0, 0);
      }
#pragma unroll
      for (int n = 0; n < 4; n++) {
        bf16x8 af = *(const bf16x8*)&w1lds[(64 + 16 * n + q) * SP + kc];
        hg[n] = __builtin_amdgcn_mfma_f32_16x16x32_bf16(af, a1[s], hg[n], 0, 0, 0);
      }
    }

    // silu + assemble GEMM2 B-fragments from OWN accumulators (sigma-permuted K)
    bf16x8 b2c[2], b2g[2];
#pragma unroll
    for (int s2 = 0; s2 < 2; s2++)
#pragma unroll
      for (int e = 0; e < 8; e++) {
        const int n = 2 * s2 + (e >> 2), j = e & 3;
        b2c[s2][e] = (short)f2bf(silu_(hc[n][j]));
        b2g[s2][e] = (short)f2bf(silu_(hg[n][j]));
      }

    // GEMM2: O[d][g] — oc/og[n2][j] = O[16n2+4p+j][g(q)]
    f32x4 oc[4], og[4];
#pragma unroll
    for (int n2 = 0; n2 < 4; n2++) {
      oc[n2] = (f32x4&)*(const float4*)(bc2 + 16 * n2 + 4 * p);
      og[n2] = (f32x4&)*(const float4*)(bg2 + 16 * n2 + 4 * p);
    }
#pragma unroll
    for (int s2 = 0; s2 < 2; s2++)
#pragma unroll
      for (int n2 = 0; n2 < 4; n2++) {
        oc[n2] = __builtin_amdgcn_mfma_f32_16x16x32_bf16(w2c[n2][s2], b2c[s2], oc[n2], 0, 0, 0);
        og[n2] = __builtin_amdgcn_mfma_f32_16x16x32_bf16(w2g[n2][s2], b2g[s2], og[n2], 0, 0, 0);
      }

    // epilogue: upd[g][d] = silu(oc)*sigm(og)*bw[bj][d]  (bw[bi] deferred to k_aggout)
    if (g0 < ng) {
      unsigned short* dst = upd + (long)g0 * KD;
      const float* wb = bwt + (long)bj * KD;
#pragma unroll
      for (int n2 = 0; n2 < 4; n2++) {
        const int d0 = 16 * n2 + 4 * p;
        float4 w = *(const float4*)(wb + d0);
        ushort4 st;
        st.x = f2bf(silu_(oc[n2][0]) * sigm(og[n2][0]) * w.x);
        st.y = f2bf(silu_(oc[n2][1]) * sigm(og[n2][1]) * w.y);
        st.z = f2bf(silu_(oc[n2][2]) * sigm(og[n2][2]) * w.z);
        st.w = f2bf(silu_(oc[n2][3]) * sigm(og[n2][3]) * w.w);
        *(ushort4*)(dst + d0) = st;
      }
    }
  }
}

// ---------------- CSR build ----------------
__global__ void k_hist(const int* __restrict__ bgr, int* __restrict__ cnt, int ng) {
  int g = blockIdx.x * blockDim.x + threadIdx.x;
  if (g < ng) atomicAdd(&cnt[bgr[3 * g + 1]], 1);
}

__global__ __launch_bounds__(256) void k_scan1(const int* __restrict__ cnt,
                                               int* __restrict__ part,
                                               int* __restrict__ bsum, int nb) {
  __shared__ int wsum[4];
  const int tid = threadIdx.x;
  const int i = blockIdx.x * 256 + tid;
  const int lane = tid & 63, w = tid >> 6;
  int orig = (i < nb) ? cnt[i] : 0;
  int v = orig;
#pragma unroll
  for (int d = 1; d < 64; d <<= 1) {
    int t = __shfl_up(v, d);
    if (lane >= d) v += t;
  }
  if (lane == 63) wsum[w] = v;
  __syncthreads();
  int add = 0;
  for (int k = 0; k < w; k++) add += wsum[k];
  v += add;
  if (i < nb) part[i] = v - orig;
  if (tid == 255) bsum[blockIdx.x] = v;
}

__global__ __launch_bounds__(1024) void k_scan2(const int* __restrict__ bsum,
                                                int* __restrict__ bscan, int nblk) {
  __shared__ int wsum[16];
  const int tid = threadIdx.x;
  const int lane = tid & 63, w = tid >> 6;
  int orig = (tid < nblk) ? bsum[tid] : 0;
  int v = orig;
#pragma unroll
  for (int d = 1; d < 64; d <<= 1) {
    int t = __shfl_up(v, d);
    if (lane >= d) v += t;
  }
  if (lane == 63) wsum[w] = v;
  __syncthreads();
  int add = 0;
  for (int k = 0; k < w; k++) add += wsum[k];
  v += add;
  if (tid < nblk) bscan[tid] = v - orig;
}

__global__ void k_scan3(const int* __restrict__ part, const int* __restrict__ bscan,
                        int* __restrict__ off, int* __restrict__ cur, int nb) {
  int i = blockIdx.x * blockDim.x + threadIdx.x;
  if (i < nb) {
    off[i] = part[i] + bscan[i >> 8];
    cur[i] = 0;
  }
}

__global__ void k_fill(const int* __restrict__ bgr, const int* __restrict__ off,
                       int* __restrict__ cur, int* __restrict__ ids, int ng) {
  int g = blockIdx.x * blockDim.x + threadIdx.x;
  if (g < ng) {
    int bi = bgr[3 * g + 1];
    int slot = atomicAdd(&cur[bi], 1);
    ids[off[bi] + slot] = g;
  }
}

// K3: segment-sum(upd) * bw[b] -> @Wo + bo + bond -> out
__global__ __launch_bounds__(256) void k_aggout(
    const float* __restrict__ bond, const float* __restrict__ bwt,
    const unsigned short* __restrict__ upd,
    const int* __restrict__ off, const int* __restrict__ cnt, const int* __restrict__ ids,
    const unsigned short* __restrict__ wot, const float* __restrict__ bo,
    float* __restrict__ out, int nb) {
  const int wave = threadIdx.x >> 6;
  const int lane = threadIdx.x & 63;
  const int r15 = lane & 15;
  const int ck = lane >> 4;
  const int base = blockIdx.x * 64 + wave * 16;
  const int b = base + r15;
  const bool bvalid = b < nb;
  const int bc = bvalid ? b : 0;
  const int o = off[bc];
  const int c = bvalid ? cnt[bc] : 0;
  const int d0 = ck * 8;

  float acc[16];
#pragma unroll
  for (int e = 0; e < 16; e++) acc[e] = 0.0f;

  int it = 0;
  for (; it + 2 <= c; it += 2) {
    const int a0 = ids[o + it];
    const int a1i = ids[o + it + 1];
    const unsigned short* r0 = upd + (long)a0 * KD;
    const unsigned short* r1 = upd + (long)a1i * KD;
    bf16x8 l0 = *(const bf16x8*)(r0 + d0);
    bf16x8 h0 = *(const bf16x8*)(r0 + 32 + d0);
    bf16x8 l1 = *(const bf16x8*)(r1 + d0);
    bf16x8 h1 = *(const bf16x8*)(r1 + 32 + d0);
#pragma unroll
    for (int e = 0; e < 8; e++) {
      acc[e]     += bf2f((unsigned short)l0[e]) + bf2f((unsigned short)l1[e]);
      acc[8 + e] += bf2f((unsigned short)h0[e]) + bf2f((unsigned short)h1[e]);
    }
  }
  if (it < c) {
    const int a0 = ids[o + it];
    const unsigned short* r0 = upd + (long)a0 * KD;
    bf16x8 l0 = *(const bf16x8*)(r0 + d0);
    bf16x8 h0 = *(const bf16x8*)(r0 + 32 + d0);
#pragma unroll
    for (int e = 0; e < 8; e++) {
      acc[e]     += bf2f((unsigned short)l0[e]);
      acc[8 + e] += bf2f((unsigned short)h0[e]);
    }
  }

  {
    const float* w = bwt + (long)bc * KD;
    float4 w0 = *(const float4*)(w + d0);
    float4 w1 = *(const float4*)(w + d0 + 4);
    float4 w2 = *(const float4*)(w + 32 + d0);
    float4 w3 = *(const float4*)(w + 32 + d0 + 4);
    acc[0] *= w0.x;  acc[1] *= w0.y;  acc[2] *= w0.z;  acc[3] *= w0.w;
    acc[4] *= w1.x;  acc[5] *= w1.y;  acc[6] *= w1.z;  acc[7] *= w1.w;
    acc[8] *= w2.x;  acc[9] *= w2.y;  acc[10] *= w2.z; acc[11] *= w2.w;
    acc[12] *= w3.x; acc[13] *= w3.y; acc[14] *= w3.z; acc[15] *= w3.w;
  }

  bf16x8 a[2];
#pragma unroll
  for (int e = 0; e < 8; e++) {
    a[0][e] = (short)f2bf(acc[e]);
    a[1][e] = (short)f2bf(acc[8 + e]);
  }

  f32x4 acc2[4];
#pragma unroll
  for (int n = 0; n < 4; n++) {
    float bv = bo[n * 16 + r15];
    acc2[n] = (f32x4){bv, bv, bv, bv};
  }
#pragma unroll
  for (int s = 0; s < 2; s++) {
    const int koff = s * 32 + ck * 8;
#pragma unroll
    for (int n = 0; n < 4; n++) {
      bf16x8 bf = *(const bf16x8*)(wot + (n * 16 + r15) * KH + koff);
      acc2[n] = __builtin_amdgcn_mfma_f32_16x16x32_bf16(a[s], bf, acc2[n], 0, 0, 0);
    }
  }
#pragma unroll
  for (int n = 0; n < 4; n++) {
#pragma unroll
    for (int j = 0; j < 4; j++) {
      const int orow = base + ck * 4 + j;
      if (orow < nb) {
        const int d = n * 16 + r15;
        out[(long)orow * KD + d] = acc2[n][j] + bond[(long)orow * KD + d];
      }
    }
  }
}

extern "C" void kernel_launch(void* const* d_in, const int* in_sizes, int n_in,
                              void* d_out, int out_size, void* d_ws, size_t ws_size,
                              hipStream_t stream) {
  const float* atom = (const float*)d_in[0];
  const float* bond = (const float*)d_in[1];
  const float* bwt  = (const float*)d_in[2];
  const float* ang  = (const float*)d_in[3];
  const int*   bgr  = (const int*)d_in[4];
  const float* wc1 = (const float*)d_in[5];
  const float* bc1 = (const float*)d_in[6];
  const float* wc2 = (const float*)d_in[7];
  const float* bc2 = (const float*)d_in[8];
  const float* wg1 = (const float*)d_in[9];
  const float* bg1 = (const float*)d_in[10];
  const float* wg2 = (const float*)d_in[11];
  const float* bg2 = (const float*)d_in[12];
  const float* wo  = (const float*)d_in[13];
  const float* bo  = (const float*)d_in[14];

  const int nb = in_sizes[1] / KD;   // bonds (200000)
  const int ng = in_sizes[4] / 3;    // angles (500000)
  float* out = (float*)d_out;

  char* p = (char*)d_ws;
  auto alloc = [&](size_t bytes) { char* r = p; p += (bytes + 255) & ~(size_t)255; return r; };
  unsigned short* wc1t = (unsigned short*)alloc((size_t)KIN * KH * 2);
  unsigned short* wg1t = (unsigned short*)alloc((size_t)KIN * KH * 2);
  unsigned short* wc2t = (unsigned short*)alloc((size_t)KH * KD * 2);
  unsigned short* wg2t = (unsigned short*)alloc((size_t)KH * KD * 2);
  unsigned short* wot  = (unsigned short*)alloc((size_t)KH * KD * 2);
  unsigned short* upd  = (unsigned short*)alloc((size_t)ng * KD * 2);
  int* cnt  = (int*)alloc((size_t)nb * 4);
  int* cur  = (int*)alloc((size_t)nb * 4);
  int* offb = (int*)alloc((size_t)nb * 4);
  int* part = (int*)alloc((size_t)nb * 4);
  int* ids  = (int*)alloc((size_t)ng * 4);
  int* bsum  = (int*)alloc(4096);
  int* bscan = (int*)alloc(4096);

  const int nblk = (nb + 255) / 256;  // 782 <= 1024

  hipMemsetAsync(cnt, 0, (size_t)nb * 4, stream);

  k_prep<<<(KIN * KH + 255) / 256, 256, 0, stream>>>(wc1, wg1, wc2, wg2, wo,
                                                     wc1t, wg1t, wc2t, wg2t, wot);

  k_angle<<<512, 256, 0, stream>>>(atom, bond, bwt, ang, bgr,
                                   wc1t, wg1t, wc2t, wg2t,
                                   bc1, bc2, bg1, bg2, upd, ng);

  k_hist<<<(ng + 255) / 256, 256, 0, stream>>>(bgr, cnt, ng);
  k_scan1<<<nblk, 256, 0, stream>>>(cnt, part, bsum, nb);
  k_scan2<<<1, 1024, 0, stream>>>(bsum, bscan, nblk);
  k_scan3<<<nblk, 256, 0, stream>>>(part, bscan, offb, cur, nb);
  k_fill<<<(ng + 255) / 256, 256, 0, stream>>>(bgr, offb, cur, ids, ng);

  const int oblocks = (nb + 63) / 64;
  k_aggout<<<oblocks, 256, 0, stream>>>(bond, bwt, upd, offb, cnt, ids,
                                        wot, bo, out, nb);
}